// Round 10
// baseline (309.223 us; speedup 1.0000x reference)
//
#include <hip/hip_runtime.h>
#include <hip/hip_bf16.h>

// PoolAggregator: out[b,h] = mean_s relu( W @ features[idx[b,s]] + bias )
// B=10000, S=32, N=100000, D_IN=512, D_H=512.
//
// Pipeline (ws >= 103 MB):
//   0) cvt_bf16: W f32 -> Wb bf16 (0.5 MB) only.
//   1) gemm_direct: H = relu(feat @ Wb^T + b) -> bf16.
//      A is NOT staged in LDS: each lane loads its MFMA fragment (2 x f32x4
//      from one feat row) straight from global (L1/L2-hot) and converts with
//      v_cvt_pk at use. LDS holds only the W bf16 double-buffer (16 KB) ->
//      16 waves/CU (VGPR-bound), the TLP hides A-load latency.
//      One __syncthreads per K-step (m97 discipline). Two-pass swizzled
//      epilogue through the 16 KB LDS overlay.
//   2) pool_mean4: out[b,:] = mean_s H[idx[b,s],:].
// Fallbacks: ws >= 102.4 MB -> f32-reg-staged gemm; else fused gather GEMM.

#define S_NB 32
#define D_IN 512
#define D_H  512
#define BM   128
#define BN   128
#define BK   32
#define NK   (D_IN / BK)            // 16
#define NNODE 100000
#define NBATCH 10000
#define NTILE_N 4
#define NTILE_M 784                 // padded so NTILES = 8 * 392, 392 % 4 == 0
#define NTILES  (NTILE_N * NTILE_M) // 3136

typedef __attribute__((ext_vector_type(8))) short  short8;
typedef __attribute__((ext_vector_type(4))) float  f32x4;
typedef __attribute__((ext_vector_type(4))) unsigned short us4;
typedef __attribute__((ext_vector_type(8))) unsigned short us8;

__device__ __forceinline__ unsigned short f2bf(float x) {
  union { float f; unsigned u; } v; v.f = x;
  unsigned r = v.u + 0x7FFFu + ((v.u >> 16) & 1u);
  return (unsigned short)(r >> 16);
}

__device__ __forceinline__ float bf2f(unsigned short x) {
  union { unsigned u; float f; } v; v.u = ((unsigned)x) << 16;
  return v.f;
}

// pack 8 f32 -> short8 of bf16 (RNE) via v_cvt_pk_bf16_f32
__device__ __forceinline__ short8 cvt8bf(f32x4 lo, f32x4 hi) {
  union { __hip_bfloat162 h; unsigned u; } c0, c1, c2, c3;
  c0.h = __float22bfloat162_rn(make_float2(lo.x, lo.y));
  c1.h = __float22bfloat162_rn(make_float2(lo.z, lo.w));
  c2.h = __float22bfloat162_rn(make_float2(hi.x, hi.y));
  c3.h = __float22bfloat162_rn(make_float2(hi.z, hi.w));
  union { unsigned u[4]; short8 s; } r;
  r.u[0] = c0.u; r.u[1] = c1.u; r.u[2] = c2.u; r.u[3] = c3.u;
  return r.s;
}

// byte offset into a [128][64]-bf16 LDS tile (row stride 128B) with XOR swizzle
// (used by fallback kernels)
__device__ __forceinline__ int swz(int row, int cb) {
  return row * 128 + (cb ^ ((row & 7) << 4));
}

// async global->LDS, 16B/lane; LDS dest wave-uniform base + lane*16
__device__ __forceinline__ void gld_lds16(const void* g, void* l) {
  __builtin_amdgcn_global_load_lds(
      (const __attribute__((address_space(1))) unsigned int*)g,
      (__attribute__((address_space(3))) unsigned int*)l, 16, 0, 0);
}

// ---------------- Phase 0: f32 -> bf16 (W only in primary path) ----------------
__global__ __launch_bounds__(256, 8)
void cvt_bf16(const float* __restrict__ src, unsigned short* __restrict__ dst, int n8) {
  int i = blockIdx.x * blockDim.x + threadIdx.x;
  const int stride = gridDim.x * blockDim.x;
  for (; i < n8; i += stride) {
    f32x4 a = *(const f32x4*)(src + (size_t)i * 8);
    f32x4 b = *(const f32x4*)(src + (size_t)i * 8 + 4);
    us8 o;
    o[0] = f2bf(a.x); o[1] = f2bf(a.y); o[2] = f2bf(a.z); o[3] = f2bf(a.w);
    o[4] = f2bf(b.x); o[5] = f2bf(b.y); o[6] = f2bf(b.z); o[7] = f2bf(b.w);
    *(us8*)(dst + (size_t)i * 8) = o;
  }
}

// ---------------- Phase 1: H = relu(feat @ Wb^T + b), A direct-to-reg ----------------
__global__ __launch_bounds__(256, 4)
void gemm_direct(const float* __restrict__ feat,
                 const unsigned short* __restrict__ Wb,
                 const float* __restrict__ bias,
                 unsigned short* __restrict__ Hb) {
  const int tid  = threadIdx.x;
  const int lane = tid & 63;
  const int wid  = tid >> 6;
  const int wr   = wid >> 1;
  const int wc   = wid & 1;

  // XCD-chunked swizzle: XCD k (bid%8) gets 392 sequential tiles, n-tile fastest.
  const int bid  = blockIdx.x;
  const int tile = (bid & 7) * (NTILES / 8) + (bid >> 3);
  const int n0   = (tile & 3) * BN;
  const int m0   = (tile >> 2) * BM;

  __shared__ __align__(16) unsigned short Ws[2][64 * 64];   // 2 x 8 KB, packed lines

  const int frow = lane & 15;
  const int jg   = lane >> 4;            // k-chunk 0..3

  // ---- A: direct per-lane row pointers (fragment = 2 x f32x4 per mi) ----
  const float* aptr[4];
#pragma unroll
  for (int mi = 0; mi < 4; ++mi) {
    int row = m0 + wr * 64 + mi * 16 + frow;
    if (row > NNODE - 1) row = NNODE - 1;              // clamp pad rows
    aptr[mi] = feat + (size_t)row * D_IN + jg * 8;
  }

  // ---- W staging: 2 DMA/wave; line L = 2 W-rows; pos p holds q = p^(L&7) ----
  const unsigned short* srcW[2];
  int dstWoff[2];
#pragma unroll
  for (int i = 0; i < 2; ++i) {
    int c = wid * 2 + i;                // chunk 0..7
    int L = c * 8 + (lane >> 3);
    int p = lane & 7;
    int q = p ^ (L & 7);
    int rowbit = q >> 2, g0 = q & 3;
    srcW[i]   = Wb + (size_t)(n0 + L * 2 + rowbit) * D_IN + g0 * 8;
    dstWoff[i] = c * 512;               // 8 lines * 64 ushorts
  }

  f32x4 acc[4][4];
#pragma unroll
  for (int i = 0; i < 4; ++i)
#pragma unroll
    for (int j = 0; j < 4; ++j)
      acc[i][j] = (f32x4){0.f, 0.f, 0.f, 0.f};

  // W fragment-read geometry (verified in rounds 8/9)
  const int wp  = ((((frow & 1) << 2) + jg) ^ ((frow >> 1) & 7)) * 16;
  const int wlb = wc * 32 + (frow >> 1);

  // ---- prologue: stage W(0) ----
#pragma unroll
  for (int i = 0; i < 2; ++i) gld_lds16(srcW[i], &Ws[0][dstWoff[i]]);
  __syncthreads();

  // ---- main loop: one __syncthreads per K-step ----
#pragma unroll
  for (int ki = 0; ki < NK; ++ki) {
    const int cur = ki & 1;

    // issue next W tile (lands during this step's compute; drained at barrier)
    if (ki < NK - 1) {
#pragma unroll
      for (int i = 0; i < 2; ++i)
        gld_lds16(srcW[i] + (ki + 1) * BK, &Ws[cur ^ 1][dstWoff[i]]);
    }

    // A fragments: direct global loads + cvt_pk (L1/L2-hot rows)
    short8 af[4];
#pragma unroll
    for (int mi = 0; mi < 4; ++mi) {
      f32x4 lo = *(const f32x4*)(aptr[mi] + ki * BK);
      f32x4 hi = *(const f32x4*)(aptr[mi] + ki * BK + 4);
      af[mi] = cvt8bf(lo, hi);
    }

    // W fragments from LDS
    short8 bfr[4];
#pragma unroll
    for (int ni = 0; ni < 4; ++ni) {
      const char* base = (const char*)&Ws[cur][0] + (wlb + ni * 8) * 128;
      bfr[ni] = *(const short8*)(base + wp);
    }

#pragma unroll
    for (int mi = 0; mi < 4; ++mi)
#pragma unroll
      for (int ni = 0; ni < 4; ++ni)
        acc[mi][ni] = __builtin_amdgcn_mfma_f32_16x16x32_bf16(af[mi], bfr[ni], acc[mi][ni], 0, 0, 0);

    __syncthreads();   // W(ki+1) landed; Ws[cur] reads retired (WAR)
  }

  // ---- Epilogue: two passes through 16 KB swizzled overlay (64 rows each) ----
  unsigned short* Cs = &Ws[0][0];       // 64 x 128 ushort = 16 KB
  const int rq = lane >> 4;
#pragma unroll
  for (int p = 0; p < 2; ++p) {
    if (wr == p) {
#pragma unroll
      for (int ni = 0; ni < 4; ++ni) {
        int col = wc * 64 + ni * 16 + frow;
        float bv = bias[n0 + col];
#pragma unroll
        for (int mi = 0; mi < 4; ++mi) {
#pragma unroll
          for (int r = 0; r < 4; ++r) {
            int lr = mi * 16 + rq * 4 + r;              // local row 0..63
            int byt = lr * 256 + ((col * 2) ^ ((lr & 7) << 4));
            *(unsigned short*)((char*)Cs + byt) = f2bf(fmaxf(acc[mi][ni][r] + bv, 0.f));
          }
        }
      }
    }
    __syncthreads();
    const int scol = (tid & 15) * 8;
#pragma unroll
    for (int it = 0; it < 4; ++it) {
      int lr   = it * 16 + (tid >> 4);                  // local row 0..63
      int grow = m0 + p * 64 + lr;
      int byt  = lr * 256 + (((tid & 15) * 16) ^ ((lr & 7) << 4));
      us8 v = *(const us8*)((const char*)Cs + byt);
      if (grow < NNODE)
        *(us8*)(Hb + (size_t)grow * D_H + n0 + scol) = v;
    }
    if (p == 0) __syncthreads();        // Cs reusable for pass 1
  }
}

// ---------------- Phase 2: out[b,:] = mean_s H[idx[b,s],:] ----------------
__global__ __launch_bounds__(256, 8)
void pool_mean4(const unsigned short* __restrict__ Hb,
                const int* __restrict__ nidx,
                float* __restrict__ out) {
  const int b4 = blockIdx.x;            // group of 4 output nodes
  const int q  = threadIdx.x >> 6;      // which node in group
  const int t  = threadIdx.x & 63;
  const int b  = b4 * 4 + q;

  __shared__ int rows[4][S_NB];
  if (threadIdx.x < 4 * S_NB)
    rows[threadIdx.x >> 5][threadIdx.x & 31] = nidx[b4 * 4 * S_NB + threadIdx.x];
  __syncthreads();

  const int c = t * 8;                  // 8 cols per thread (16B loads)
  float s0 = 0.f, s1 = 0.f, s2 = 0.f, s3 = 0.f;
  float s4 = 0.f, s5 = 0.f, s6 = 0.f, s7 = 0.f;
#pragma unroll
  for (int s = 0; s < S_NB; ++s) {
    us8 v = *(const us8*)(Hb + (size_t)rows[q][s] * D_H + c);
    s0 += bf2f(v[0]); s1 += bf2f(v[1]); s2 += bf2f(v[2]); s3 += bf2f(v[3]);
    s4 += bf2f(v[4]); s5 += bf2f(v[5]); s6 += bf2f(v[6]); s7 += bf2f(v[7]);
  }
  const float inv = 1.0f / (float)S_NB;
  f32x4 o1; o1.x = s0 * inv; o1.y = s1 * inv; o1.z = s2 * inv; o1.w = s3 * inv;
  f32x4 o2; o2.x = s4 * inv; o2.y = s5 * inv; o2.z = s6 * inv; o2.w = s7 * inv;
  *(f32x4*)(out + (size_t)b * D_H + c)     = o1;
  *(f32x4*)(out + (size_t)b * D_H + c + 4) = o2;
}

// ---------------- Fallback A: f32 reg-staged GEMM ----------------
__global__ __launch_bounds__(256, 4)
void gemm_h(const float* __restrict__ feat,
            const float* __restrict__ Wm,
            const float* __restrict__ bias,
            unsigned short* __restrict__ Hb) {
  const int tid  = threadIdx.x;
  const int lane = tid & 63;
  const int wid  = tid >> 6;
  const int wr   = wid >> 1;
  const int wc   = wid & 1;
  const int n0   = blockIdx.x * BN;
  const int m0   = blockIdx.y * BM;

  __shared__ __align__(16) unsigned short As[BM * 64];
  __shared__ __align__(16) unsigned short Bs[BM * 64];

  const int lr = tid >> 4;
  const int lc = tid & 15;

  const float* aptr[8];
  const float* wptr[8];
#pragma unroll
  for (int p = 0; p < 8; ++p) {
    int row = p * 16 + lr;
    int gr  = m0 + row; if (gr > NNODE - 1) gr = NNODE - 1;
    aptr[p] = feat + (size_t)gr * D_IN + lc * 4;
    wptr[p] = Wm + (size_t)(n0 + row) * D_IN + lc * 4;
  }

  f32x4 acc[4][4];
#pragma unroll
  for (int i = 0; i < 4; ++i)
#pragma unroll
    for (int j = 0; j < 4; ++j)
      acc[i][j] = (f32x4){0.f, 0.f, 0.f, 0.f};

  const int frow = lane & 15;
  const int kcb  = (lane >> 4) * 16;
  const int arow = wr * 64 + frow;
  const int brow = wc * 64 + frow;

  for (int k0 = 0; k0 < D_IN; k0 += 64) {
    __syncthreads();
#pragma unroll
    for (int p = 0; p < 8; ++p) {
      int row = p * 16 + lr;
      f32x4 av = *(const f32x4*)(aptr[p] + k0);
      f32x4 wv = *(const f32x4*)(wptr[p] + k0);
      us4 a4, w4;
      a4.x = f2bf(av.x); a4.y = f2bf(av.y); a4.z = f2bf(av.z); a4.w = f2bf(av.w);
      w4.x = f2bf(wv.x); w4.y = f2bf(wv.y); w4.z = f2bf(wv.z); w4.w = f2bf(wv.w);
      *(us4*)((char*)As + swz(row, lc * 8)) = a4;
      *(us4*)((char*)Bs + swz(row, lc * 8)) = w4;
    }
    __syncthreads();

#pragma unroll
    for (int kk = 0; kk < 2; ++kk) {
      short8 af[4], bfr[4];
#pragma unroll
      for (int mi = 0; mi < 4; ++mi)
        af[mi] = *(const short8*)((const char*)As + swz(arow + mi * 16, kk * 64 + kcb));
#pragma unroll
      for (int ni = 0; ni < 4; ++ni)
        bfr[ni] = *(const short8*)((const char*)Bs + swz(brow + ni * 16, kk * 64 + kcb));
#pragma unroll
      for (int mi = 0; mi < 4; ++mi)
#pragma unroll
        for (int ni = 0; ni < 4; ++ni)
          acc[mi][ni] = __builtin_amdgcn_mfma_f32_16x16x32_bf16(af[mi], bfr[ni], acc[mi][ni], 0, 0, 0);
    }
  }

  const int rq = lane >> 4;
#pragma unroll
  for (int ni = 0; ni < 4; ++ni) {
    int col = n0 + wc * 64 + ni * 16 + frow;
    float bv = bias[col];
#pragma unroll
    for (int mi = 0; mi < 4; ++mi) {
#pragma unroll
      for (int r = 0; r < 4; ++r) {
        int grow = m0 + wr * 64 + mi * 16 + rq * 4 + r;
        if (grow < NNODE)
          Hb[(size_t)grow * D_H + col] = f2bf(fmaxf(acc[mi][ni][r] + bv, 0.f));
      }
    }
  }
}

// ---------------- Fallback B: fused gathered GEMM (round-1) ----------------
__global__ __launch_bounds__(256, 4)
void pool_aggr_gemm(const int* __restrict__ nidx_g,
                    const float* __restrict__ feat,
                    const float* __restrict__ Wm,
                    const float* __restrict__ bias,
                    float* __restrict__ out) {
  const int tid  = threadIdx.x;
  const int lane = tid & 63;
  const int wid  = tid >> 6;
  const int wr   = wid >> 1;
  const int wc   = wid & 1;
  const int n0   = blockIdx.x * BN;
  const int mb   = blockIdx.y;

  __shared__ __align__(16) unsigned short As[BM * 64];
  __shared__ __align__(16) unsigned short Bs[BM * 64];
  __shared__ int nid[BM];

  if (tid < BM) nid[tid] = nidx_g[mb * BM + tid];
  __syncthreads();

  const int lr = tid >> 4;
  const int lc = tid & 15;

  const float* aptr[8];
  const float* wptr[8];
#pragma unroll
  for (int p = 0; p < 8; ++p) {
    int row = p * 16 + lr;
    aptr[p] = feat + (size_t)nid[row] * D_IN + lc * 4;
    wptr[p] = Wm + (size_t)(n0 + row) * D_IN + lc * 4;
  }

  f32x4 acc[4][4];
#pragma unroll
  for (int i = 0; i < 4; ++i)
#pragma unroll
    for (int j = 0; j < 4; ++j)
      acc[i][j] = (f32x4){0.f, 0.f, 0.f, 0.f};

  const int frow = lane & 15;
  const int kcb  = (lane >> 4) * 16;
  const int arow = wr * 64 + frow;
  const int brow = wc * 64 + frow;

  for (int k0 = 0; k0 < D_IN; k0 += 64) {
    __syncthreads();
#pragma unroll
    for (int p = 0; p < 8; ++p) {
      int row = p * 16 + lr;
      f32x4 av = *(const f32x4*)(aptr[p] + k0);
      f32x4 wv = *(const f32x4*)(wptr[p] + k0);
      us4 a4, w4;
      a4.x = f2bf(av.x); a4.y = f2bf(av.y); a4.z = f2bf(av.z); a4.w = f2bf(av.w);
      w4.x = f2bf(wv.x); w4.y = f2bf(wv.y); w4.z = f2bf(wv.z); w4.w = f2bf(wv.w);
      *(us4*)((char*)As + swz(row, lc * 8)) = a4;
      *(us4*)((char*)Bs + swz(row, lc * 8)) = w4;
    }
    __syncthreads();

#pragma unroll
    for (int kk = 0; kk < 2; ++kk) {
      short8 af[4], bfr[4];
#pragma unroll
      for (int mi = 0; mi < 4; ++mi)
        af[mi] = *(const short8*)((const char*)As + swz(arow + mi * 16, kk * 64 + kcb));
#pragma unroll
      for (int ni = 0; ni < 4; ++ni)
        bfr[ni] = *(const short8*)((const char*)Bs + swz(brow + ni * 16, kk * 64 + kcb));
#pragma unroll
      for (int mi = 0; mi < 4; ++mi)
#pragma unroll
        for (int ni = 0; ni < 4; ++ni)
          acc[mi][ni] = __builtin_amdgcn_mfma_f32_16x16x32_bf16(af[mi], bfr[ni], acc[mi][ni], 0, 0, 0);
    }
  }

  const int rq = lane >> 4;
#pragma unroll
  for (int ni = 0; ni < 4; ++ni) {
    int col = n0 + wc * 64 + ni * 16 + frow;
    float bv = bias[col];
#pragma unroll
    for (int bl = 0; bl < 2; ++bl) {
      float s = 0.f;
#pragma unroll
      for (int m2 = 0; m2 < 2; ++m2) {
        int mi = bl * 2 + m2;
#pragma unroll
        for (int r = 0; r < 4; ++r)
          s += fmaxf(acc[mi][ni][r] + bv, 0.f);
      }
      s += __shfl_xor(s, 16);
      s += __shfl_xor(s, 32);
      if (rq == 0) {
        int bb = mb * 4 + wr * 2 + bl;
        out[(size_t)bb * D_H + col] = s * (1.0f / (float)S_NB);
      }
    }
  }
}

extern "C" void kernel_launch(void* const* d_in, const int* in_sizes, int n_in,
                              void* d_out, int out_size, void* d_ws, size_t ws_size,
                              hipStream_t stream) {
  const int*   nidx = (const int*)d_in[0];    // [10000,32]
  const float* feat = (const float*)d_in[1];  // [100000,512]
  const float* Wm   = (const float*)d_in[2];  // [512,512]
  const float* bias = (const float*)d_in[3];  // [512]
  float* out = (float*)d_out;                 // [10000,512]

  const size_t wb_elems = (size_t)D_H * D_IN;                           // 262144
  const size_t wb_bytes = wb_elems * sizeof(unsigned short);            // 0.5 MB
  const size_t h_bytes  = (size_t)NNODE * D_H * sizeof(unsigned short); // 102.4 MB

  if (ws_size >= wb_bytes + h_bytes) {
    unsigned short* Wb = (unsigned short*)d_ws;
    unsigned short* Hb = Wb + wb_elems;
    cvt_bf16<<<128, 256, 0, stream>>>(Wm, Wb, D_H * D_IN / 8);
    gemm_direct<<<NTILES, 256, 0, stream>>>(feat, Wb, bias, Hb);
    pool_mean4<<<NBATCH / 4, 256, 0, stream>>>(Hb, nidx, out);
  } else if (ws_size >= h_bytes) {
    unsigned short* Hb = (unsigned short*)d_ws;
    dim3 g1(D_H / BN, (NNODE + BM - 1) / BM);
    gemm_h<<<g1, 256, 0, stream>>>(feat, Wm, bias, Hb);
    pool_mean4<<<NBATCH / 4, 256, 0, stream>>>(Hb, nidx, out);
  } else {
    dim3 grid(D_H / BN, NBATCH / 4);
    pool_aggr_gemm<<<grid, 256, 0, stream>>>(nidx, feat, Wm, bias, out);
  }
}

// Round 11
// 187.272 us; speedup vs baseline: 1.6512x; 1.6512x over previous
//
#include <hip/hip_runtime.h>
#include <hip/hip_bf16.h>

// PoolAggregator: out[b,h] = mean_s relu( W @ features[idx[b,s]] + bias )
// B=10000, S=32, N=100000, D_IN=512, D_H=512.
//
// Pipeline (ws >= 103 MB):
//   0) cvt_bf16: W f32 -> Wb bf16 (0.5 MB) only.
//   1) gemm_big: H = relu(feat @ Wb^T + b) -> bf16.
//      R9 analysis: the 128x128/2x2-wave kernel saturates the LDS pipe
//      (~118 B/cyc of 128). This kernel cuts LDS bytes/FLOP ~30%:
//      256x128 block tile, 4 M-stacked waves (64x128 each) -> A fragments
//      read once (not twice); A f32 DMA dbuf 64KB + W bf16 dbuf 16KB = 80KB,
//      2 blocks/CU, acc[4][8] (128 VGPR), launch_bounds(256,2).
//      T4 loop: counted s_waitcnt vmcnt(10) + raw barriers (proven in R9).
//   2) pool_mean4: out[b,:] = mean_s H[idx[b,s],:].
// Fallbacks: ws >= 102.4 MB -> f32-reg-staged gemm; else fused gather GEMM.

#define S_NB 32
#define D_IN 512
#define D_H  512
#define BM   256
#define BN   128
#define BK   32
#define NK   (D_IN / BK)            // 16
#define NNODE 100000
#define NBATCH 10000
#define NTILE_N 4
#define NTILE_M 392                 // 392*256 = 100352 >= 100000; 1568 = 8*196, 196%4==0
#define NTILES  (NTILE_N * NTILE_M) // 1568

typedef __attribute__((ext_vector_type(8))) short  short8;
typedef __attribute__((ext_vector_type(4))) float  f32x4;
typedef __attribute__((ext_vector_type(4))) unsigned short us4;
typedef __attribute__((ext_vector_type(8))) unsigned short us8;

__device__ __forceinline__ unsigned short f2bf(float x) {
  union { float f; unsigned u; } v; v.f = x;
  unsigned r = v.u + 0x7FFFu + ((v.u >> 16) & 1u);
  return (unsigned short)(r >> 16);
}

__device__ __forceinline__ float bf2f(unsigned short x) {
  union { unsigned u; float f; } v; v.u = ((unsigned)x) << 16;
  return v.f;
}

// pack 8 f32 -> short8 of bf16 (RNE) via v_cvt_pk_bf16_f32
__device__ __forceinline__ short8 cvt8bf(f32x4 lo, f32x4 hi) {
  union { __hip_bfloat162 h; unsigned u; } c0, c1, c2, c3;
  c0.h = __float22bfloat162_rn(make_float2(lo.x, lo.y));
  c1.h = __float22bfloat162_rn(make_float2(lo.z, lo.w));
  c2.h = __float22bfloat162_rn(make_float2(hi.x, hi.y));
  c3.h = __float22bfloat162_rn(make_float2(hi.z, hi.w));
  union { unsigned u[4]; short8 s; } r;
  r.u[0] = c0.u; r.u[1] = c1.u; r.u[2] = c2.u; r.u[3] = c3.u;
  return r.s;
}

// byte offset into a [128][64]-bf16 LDS tile (row stride 128B) with XOR swizzle
// (used by fallback kernels)
__device__ __forceinline__ int swz(int row, int cb) {
  return row * 128 + (cb ^ ((row & 7) << 4));
}

// async global->LDS, 16B/lane; LDS dest wave-uniform base + lane*16
__device__ __forceinline__ void gld_lds16(const void* g, void* l) {
  __builtin_amdgcn_global_load_lds(
      (const __attribute__((address_space(1))) unsigned int*)g,
      (__attribute__((address_space(3))) unsigned int*)l, 16, 0, 0);
}

// ---------------- Phase 0: f32 -> bf16 (W only in primary path) ----------------
__global__ __launch_bounds__(256, 8)
void cvt_bf16(const float* __restrict__ src, unsigned short* __restrict__ dst, int n8) {
  int i = blockIdx.x * blockDim.x + threadIdx.x;
  const int stride = gridDim.x * blockDim.x;
  for (; i < n8; i += stride) {
    f32x4 a = *(const f32x4*)(src + (size_t)i * 8);
    f32x4 b = *(const f32x4*)(src + (size_t)i * 8 + 4);
    us8 o;
    o[0] = f2bf(a.x); o[1] = f2bf(a.y); o[2] = f2bf(a.z); o[3] = f2bf(a.w);
    o[4] = f2bf(b.x); o[5] = f2bf(b.y); o[6] = f2bf(b.z); o[7] = f2bf(b.w);
    *(us8*)(dst + (size_t)i * 8) = o;
  }
}

// ---------------- Phase 1: H = relu(feat @ Wb^T + b), 256x128 tile ----------------
__global__ __launch_bounds__(256, 2)
void gemm_big(const float* __restrict__ feat,
              const unsigned short* __restrict__ Wb,
              const float* __restrict__ bias,
              unsigned short* __restrict__ Hb) {
  const int tid  = threadIdx.x;
  const int lane = tid & 63;
  const int wid  = tid >> 6;             // wave 0..3, owns rows [64w, 64w+64)

  // XCD-chunked swizzle: XCD k (bid%8) gets 196 sequential tiles, n-tile fastest.
  const int bid  = blockIdx.x;
  const int tile = (bid & 7) * (NTILES / 8) + (bid >> 3);
  const int n0   = (tile & 3) * BN;
  const int m0   = (tile >> 2) * BM;

  __shared__ __align__(16) float          As[2][BM * BK];   // 2 x 32 KB (f32)
  __shared__ __align__(16) unsigned short Ws[2][64 * 64];   // 2 x 8 KB, packed lines

  const int frow = lane & 15;
  const int jg   = lane >> 4;            // k-chunk 0..3

  // ---- A staging: 8 DMA/wave, rows [64w+8i .. +7], granule-swizzled source ----
  const float* srcA[8];
  int dstAoff[8];
#pragma unroll
  for (int i = 0; i < 8; ++i) {
    int row = wid * 64 + i * 8 + (lane >> 3);
    int p   = lane & 7;
    int gr  = m0 + row; if (gr > NNODE - 1) gr = NNODE - 1;     // clamp pad rows
    srcA[i]   = feat + (size_t)gr * D_IN + (p ^ (row & 7)) * 4; // pre-swizzled src
    dstAoff[i] = (wid * 64 + i * 8) * BK;
  }

  // ---- W staging: 2 DMA/wave; line L = 2 W-rows; pos p holds q = p^(L&7) ----
  const unsigned short* srcW[2];
  int dstWoff[2];
#pragma unroll
  for (int i = 0; i < 2; ++i) {
    int c = wid * 2 + i;                // chunk 0..7
    int L = c * 8 + (lane >> 3);
    int p = lane & 7;
    int q = p ^ (L & 7);
    int rowbit = q >> 2, g0 = q & 3;
    srcW[i]   = Wb + (size_t)(n0 + L * 2 + rowbit) * D_IN + g0 * 8;
    dstWoff[i] = c * 512;               // 8 lines * 64 ushorts
  }

  f32x4 acc[4][8];
#pragma unroll
  for (int i = 0; i < 4; ++i)
#pragma unroll
    for (int j = 0; j < 8; ++j)
      acc[i][j] = (f32x4){0.f, 0.f, 0.f, 0.f};

  // ---- fragment-read geometry (all byte offsets static) ----
  const int ag1 = ((2 * jg) ^ (frow & 7)) * 16;
  const int ag2 = ((2 * jg + 1) ^ (frow & 7)) * 16;
  const int wp  = ((((frow & 1) << 2) + jg) ^ ((frow >> 1) & 7)) * 16;
  const int wlb = frow >> 1;

  // ---- prologue: issue K-tile 0 DMAs ----
#pragma unroll
  for (int i = 0; i < 8; ++i) gld_lds16(srcA[i], &As[0][dstAoff[i]]);
#pragma unroll
  for (int i = 0; i < 2; ++i) gld_lds16(srcW[i], &Ws[0][dstWoff[i]]);

  // ---- main loop: counted vmcnt + 2 raw barriers per K-step (T4, R9-proven) ----
#pragma unroll
  for (int ki = 0; ki < NK; ++ki) {
    const int cur = ki & 1;

    if (ki < NK - 1) {
#pragma unroll
      for (int i = 0; i < 8; ++i)
        gld_lds16(srcA[i] + (ki + 1) * BK, &As[cur ^ 1][dstAoff[i]]);
#pragma unroll
      for (int i = 0; i < 2; ++i)
        gld_lds16(srcW[i] + (ki + 1) * BK, &Ws[cur ^ 1][dstWoff[i]]);
      asm volatile("s_waitcnt vmcnt(10)" ::: "memory");  // DMA(ki) landed; DMA(ki+1) in flight
    } else {
      asm volatile("s_waitcnt vmcnt(0)" ::: "memory");
    }
    __builtin_amdgcn_s_barrier();                        // everyone's DMA(ki) visible
    __builtin_amdgcn_sched_barrier(0);

    // A fragments (f32 LDS -> cvt_pk -> bf16)
    short8 af[4];
#pragma unroll
    for (int mi = 0; mi < 4; ++mi) {
      const char* base = (const char*)&As[cur][0] + (wid * 64 + mi * 16 + frow) * 128;
      f32x4 lo = *(const f32x4*)(base + ag1);
      f32x4 hi = *(const f32x4*)(base + ag2);
      af[mi] = cvt8bf(lo, hi);
    }
    // W fragments (all 128 cols)
    short8 bfr[8];
#pragma unroll
    for (int ni = 0; ni < 8; ++ni) {
      const char* base = (const char*)&Ws[cur][0] + (wlb + ni * 8) * 128;
      bfr[ni] = *(const short8*)(base + wp);
    }
#pragma unroll
    for (int mi = 0; mi < 4; ++mi)
#pragma unroll
      for (int ni = 0; ni < 8; ++ni)
        acc[mi][ni] = __builtin_amdgcn_mfma_f32_16x16x32_bf16(af[mi], bfr[ni], acc[mi][ni], 0, 0, 0);

    asm volatile("s_waitcnt lgkmcnt(0)" ::: "memory");   // my LDS reads retired
    __builtin_amdgcn_s_barrier();                        // buf[cur] reusable
    __builtin_amdgcn_sched_barrier(0);
  }

  // ---- Epilogue: bias+ReLU -> bf16 via XOR-swizzled 64KB overlay on As ----
  unsigned short* Cs = (unsigned short*)&As[0][0];       // 256 x 128 ushort = 64 KB
  const int rq = lane >> 4;
#pragma unroll
  for (int ni = 0; ni < 8; ++ni) {
    int col = ni * 16 + frow;
    float bv = bias[n0 + col];
#pragma unroll
    for (int mi = 0; mi < 4; ++mi) {
#pragma unroll
      for (int r = 0; r < 4; ++r) {
        int row = wid * 64 + mi * 16 + rq * 4 + r;
        int byt = row * 256 + ((col * 2) ^ ((row & 7) << 4));
        *(unsigned short*)((char*)Cs + byt) = f2bf(fmaxf(acc[mi][ni][r] + bv, 0.f));
      }
    }
  }
  __syncthreads();

  const int scol = (tid & 15) * 8;
#pragma unroll
  for (int it = 0; it < 16; ++it) {
    int row  = it * 16 + (tid >> 4);
    int grow = m0 + row;
    int byt  = row * 256 + (((tid & 15) * 16) ^ ((row & 7) << 4));
    us8 v = *(const us8*)((const char*)Cs + byt);
    if (grow < NNODE)
      *(us8*)(Hb + (size_t)grow * D_H + n0 + scol) = v;
  }
}

// ---------------- Phase 2: out[b,:] = mean_s H[idx[b,s],:] ----------------
__global__ __launch_bounds__(256, 8)
void pool_mean4(const unsigned short* __restrict__ Hb,
                const int* __restrict__ nidx,
                float* __restrict__ out) {
  const int b4 = blockIdx.x;            // group of 4 output nodes
  const int q  = threadIdx.x >> 6;      // which node in group
  const int t  = threadIdx.x & 63;
  const int b  = b4 * 4 + q;

  __shared__ int rows[4][S_NB];
  if (threadIdx.x < 4 * S_NB)
    rows[threadIdx.x >> 5][threadIdx.x & 31] = nidx[b4 * 4 * S_NB + threadIdx.x];
  __syncthreads();

  const int c = t * 8;                  // 8 cols per thread (16B loads)
  float s0 = 0.f, s1 = 0.f, s2 = 0.f, s3 = 0.f;
  float s4 = 0.f, s5 = 0.f, s6 = 0.f, s7 = 0.f;
#pragma unroll
  for (int s = 0; s < S_NB; ++s) {
    us8 v = *(const us8*)(Hb + (size_t)rows[q][s] * D_H + c);
    s0 += bf2f(v[0]); s1 += bf2f(v[1]); s2 += bf2f(v[2]); s3 += bf2f(v[3]);
    s4 += bf2f(v[4]); s5 += bf2f(v[5]); s6 += bf2f(v[6]); s7 += bf2f(v[7]);
  }
  const float inv = 1.0f / (float)S_NB;
  f32x4 o1; o1.x = s0 * inv; o1.y = s1 * inv; o1.z = s2 * inv; o1.w = s3 * inv;
  f32x4 o2; o2.x = s4 * inv; o2.y = s5 * inv; o2.z = s6 * inv; o2.w = s7 * inv;
  *(f32x4*)(out + (size_t)b * D_H + c)     = o1;
  *(f32x4*)(out + (size_t)b * D_H + c + 4) = o2;
}

// ---------------- Fallback A: f32 reg-staged GEMM ----------------
__global__ __launch_bounds__(256, 4)
void gemm_h(const float* __restrict__ feat,
            const float* __restrict__ Wm,
            const float* __restrict__ bias,
            unsigned short* __restrict__ Hb) {
  const int tid  = threadIdx.x;
  const int lane = tid & 63;
  const int wid  = tid >> 6;
  const int wr   = wid >> 1;
  const int wc   = wid & 1;
  const int n0   = blockIdx.x * BN;
  const int m0   = blockIdx.y * 128;

  __shared__ __align__(16) unsigned short As[128 * 64];
  __shared__ __align__(16) unsigned short Bs[128 * 64];

  const int lr = tid >> 4;
  const int lc = tid & 15;

  const float* aptr[8];
  const float* wptr[8];
#pragma unroll
  for (int p = 0; p < 8; ++p) {
    int row = p * 16 + lr;
    int gr  = m0 + row; if (gr > NNODE - 1) gr = NNODE - 1;
    aptr[p] = feat + (size_t)gr * D_IN + lc * 4;
    wptr[p] = Wm + (size_t)(n0 + row) * D_IN + lc * 4;
  }

  f32x4 acc[4][4];
#pragma unroll
  for (int i = 0; i < 4; ++i)
#pragma unroll
    for (int j = 0; j < 4; ++j)
      acc[i][j] = (f32x4){0.f, 0.f, 0.f, 0.f};

  const int frow = lane & 15;
  const int kcb  = (lane >> 4) * 16;
  const int arow = wr * 64 + frow;
  const int brow = wc * 64 + frow;

  for (int k0 = 0; k0 < D_IN; k0 += 64) {
    __syncthreads();
#pragma unroll
    for (int p = 0; p < 8; ++p) {
      int row = p * 16 + lr;
      f32x4 av = *(const f32x4*)(aptr[p] + k0);
      f32x4 wv = *(const f32x4*)(wptr[p] + k0);
      us4 a4, w4;
      a4.x = f2bf(av.x); a4.y = f2bf(av.y); a4.z = f2bf(av.z); a4.w = f2bf(av.w);
      w4.x = f2bf(wv.x); w4.y = f2bf(wv.y); w4.z = f2bf(wv.z); w4.w = f2bf(wv.w);
      *(us4*)((char*)As + swz(row, lc * 8)) = a4;
      *(us4*)((char*)Bs + swz(row, lc * 8)) = w4;
    }
    __syncthreads();

#pragma unroll
    for (int kk = 0; kk < 2; ++kk) {
      short8 af[4], bfr[4];
#pragma unroll
      for (int mi = 0; mi < 4; ++mi)
        af[mi] = *(const short8*)((const char*)As + swz(arow + mi * 16, kk * 64 + kcb));
#pragma unroll
      for (int ni = 0; ni < 4; ++ni)
        bfr[ni] = *(const short8*)((const char*)Bs + swz(brow + ni * 16, kk * 64 + kcb));
#pragma unroll
      for (int mi = 0; mi < 4; ++mi)
#pragma unroll
        for (int ni = 0; ni < 4; ++ni)
          acc[mi][ni] = __builtin_amdgcn_mfma_f32_16x16x32_bf16(af[mi], bfr[ni], acc[mi][ni], 0, 0, 0);
    }
  }

  const int rq = lane >> 4;
#pragma unroll
  for (int ni = 0; ni < 4; ++ni) {
    int col = n0 + wc * 64 + ni * 16 + frow;
    float bv = bias[col];
#pragma unroll
    for (int mi = 0; mi < 4; ++mi) {
#pragma unroll
      for (int r = 0; r < 4; ++r) {
        int grow = m0 + wr * 64 + mi * 16 + rq * 4 + r;
        if (grow < NNODE)
          Hb[(size_t)grow * D_H + col] = f2bf(fmaxf(acc[mi][ni][r] + bv, 0.f));
      }
    }
  }
}

// ---------------- Fallback B: fused gathered GEMM (round-1) ----------------
__global__ __launch_bounds__(256, 4)
void pool_aggr_gemm(const int* __restrict__ nidx_g,
                    const float* __restrict__ feat,
                    const float* __restrict__ Wm,
                    const float* __restrict__ bias,
                    float* __restrict__ out) {
  const int tid  = threadIdx.x;
  const int lane = tid & 63;
  const int wid  = tid >> 6;
  const int wr   = wid >> 1;
  const int wc   = wid & 1;
  const int n0   = blockIdx.x * BN;
  const int mb   = blockIdx.y;

  __shared__ __align__(16) unsigned short As[128 * 64];
  __shared__ __align__(16) unsigned short Bs[128 * 64];
  __shared__ int nid[128];

  if (tid < 128) nid[tid] = nidx_g[mb * 128 + tid];
  __syncthreads();

  const int lr = tid >> 4;
  const int lc = tid & 15;

  const float* aptr[8];
  const float* wptr[8];
#pragma unroll
  for (int p = 0; p < 8; ++p) {
    int row = p * 16 + lr;
    aptr[p] = feat + (size_t)nid[row] * D_IN + lc * 4;
    wptr[p] = Wm + (size_t)(n0 + row) * D_IN + lc * 4;
  }

  f32x4 acc[4][4];
#pragma unroll
  for (int i = 0; i < 4; ++i)
#pragma unroll
    for (int j = 0; j < 4; ++j)
      acc[i][j] = (f32x4){0.f, 0.f, 0.f, 0.f};

  const int frow = lane & 15;
  const int kcb  = (lane >> 4) * 16;
  const int arow = wr * 64 + frow;
  const int brow = wc * 64 + frow;

  for (int k0 = 0; k0 < D_IN; k0 += 64) {
    __syncthreads();
#pragma unroll
    for (int p = 0; p < 8; ++p) {
      int row = p * 16 + lr;
      f32x4 av = *(const f32x4*)(aptr[p] + k0);
      f32x4 wv = *(const f32x4*)(wptr[p] + k0);
      us4 a4, w4;
      a4.x = f2bf(av.x); a4.y = f2bf(av.y); a4.z = f2bf(av.z); a4.w = f2bf(av.w);
      w4.x = f2bf(wv.x); w4.y = f2bf(wv.y); w4.z = f2bf(wv.z); w4.w = f2bf(wv.w);
      *(us4*)((char*)As + swz(row, lc * 8)) = a4;
      *(us4*)((char*)Bs + swz(row, lc * 8)) = w4;
    }
    __syncthreads();

#pragma unroll
    for (int kk = 0; kk < 2; ++kk) {
      short8 af[4], bfr[4];
#pragma unroll
      for (int mi = 0; mi < 4; ++mi)
        af[mi] = *(const short8*)((const char*)As + swz(arow + mi * 16, kk * 64 + kcb));
#pragma unroll
      for (int ni = 0; ni < 4; ++ni)
        bfr[ni] = *(const short8*)((const char*)Bs + swz(brow + ni * 16, kk * 64 + kcb));
#pragma unroll
      for (int mi = 0; mi < 4; ++mi)
#pragma unroll
        for (int ni = 0; ni < 4; ++ni)
          acc[mi][ni] = __builtin_amdgcn_mfma_f32_16x16x32_bf16(af[mi], bfr[ni], acc[mi][ni], 0, 0, 0);
    }
  }

  const int rq = lane >> 4;
#pragma unroll
  for (int ni = 0; ni < 4; ++ni) {
    int col = n0 + wc * 64 + ni * 16 + frow;
    float bv = bias[col];
#pragma unroll
    for (int bl = 0; bl < 2; ++bl) {
      float s = 0.f;
#pragma unroll
      for (int m2 = 0; m2 < 2; ++m2) {
        int mi = bl * 2 + m2;
#pragma unroll
        for (int r = 0; r < 4; ++r)
          s += fmaxf(acc[mi][ni][r] + bv, 0.f);
      }
      s += __shfl_xor(s, 16);
      s += __shfl_xor(s, 32);
      if (rq == 0) {
        int bb = mb * 4 + wr * 2 + bl;
        out[(size_t)bb * D_H + col] = s * (1.0f / (float)S_NB);
      }
    }
  }
}

extern "C" void kernel_launch(void* const* d_in, const int* in_sizes, int n_in,
                              void* d_out, int out_size, void* d_ws, size_t ws_size,
                              hipStream_t stream) {
  const int*   nidx = (const int*)d_in[0];    // [10000,32]
  const float* feat = (const float*)d_in[1];  // [100000,512]
  const float* Wm   = (const float*)d_in[2];  // [512,512]
  const float* bias = (const float*)d_in[3];  // [512]
  float* out = (float*)d_out;                 // [10000,512]

  const size_t wb_elems = (size_t)D_H * D_IN;                           // 262144
  const size_t wb_bytes = wb_elems * sizeof(unsigned short);            // 0.5 MB
  const size_t h_bytes  = (size_t)NNODE * D_H * sizeof(unsigned short); // 102.4 MB

  if (ws_size >= wb_bytes + h_bytes) {
    unsigned short* Wb = (unsigned short*)d_ws;
    unsigned short* Hb = Wb + wb_elems;
    cvt_bf16<<<128, 256, 0, stream>>>(Wm, Wb, D_H * D_IN / 8);
    gemm_big<<<NTILES, 256, 0, stream>>>(feat, Wb, bias, Hb);
    pool_mean4<<<NBATCH / 4, 256, 0, stream>>>(Hb, nidx, out);
  } else if (ws_size >= h_bytes) {
    unsigned short* Hb = (unsigned short*)d_ws;
    dim3 g1(D_H / BN, (NNODE + 127) / 128);
    gemm_h<<<g1, 256, 0, stream>>>(feat, Wm, bias, Hb);
    pool_mean4<<<NBATCH / 4, 256, 0, stream>>>(Hb, nidx, out);
  } else {
    dim3 grid(D_H / BN, NBATCH / 4);
    pool_aggr_gemm<<<grid, 256, 0, stream>>>(nidx, feat, Wm, bias, out);
  }
}